// Round 11
// baseline (81.426 us; speedup 1.0000x reference)
//
#include <hip/hip_runtime.h>

// out[g,i,j,:] = edge_attr[e] at edge cells (unique, off-diag), emb_table[1] on
// in-graph diagonal, emb_table[2] elsewhere.
// Uniform fused path (TN == B*N, pow2 N/D4, ws >= cells*4):
//   K1: map[cells] = -1 (persistent grid-stride).
//   K2: map[s*N + dj] = e per edge.
//   K3: single full-output pass; every unit stored exactly once, value muxed
//       from map (no store predication -> dense 64B store granules).
// Fallbacks: R10 uniform 2-pass, R8 generic, R1 basic.

typedef float f4 __attribute__((ext_vector_type(4)));

// ---------------- uniform fused path ----------------

__global__ __launch_bounds__(256) void mapinit_kernel(int4* __restrict__ map4,
                                                      long long n4) {
    long long idx = (long long)blockIdx.x * 256 + threadIdx.x;
    long long stride = (long long)gridDim.x * 256;
    int4 mi = make_int4(-1, -1, -1, -1);
    for (; idx < n4; idx += stride) map4[idx] = mi;
}

__global__ __launch_bounds__(256) void mapscat_kernel(const int* __restrict__ eidx,
                                                      int* __restrict__ map,
                                                      int E, int N) {
    int e = blockIdx.x * blockDim.x + threadIdx.x;
    if (e >= E) return;
    int s = eidx[e];                    // global src == global row id (uniform)
    int d = eidx[E + e];
    map[(size_t)s * N + (d & (N - 1))] = e;
}

__global__ __launch_bounds__(256) void fused_u_kernel(
        const f4* __restrict__ attr, const f4* __restrict__ emb,
        const int* __restrict__ map, f4* __restrict__ out,
        long long total4, int D4, int lg, int lgN) {
    long long base0 = ((long long)blockIdx.x << 11) + threadIdx.x;
    long long stride = (long long)gridDim.x << 11;
    int d4 = (int)base0 & (D4 - 1);
    f4 v1 = emb[D4 + d4];          // diag
    f4 v2 = emb[2 * D4 + d4];      // background
    int Nm1 = (1 << lgN) - 1;
    for (long long base = base0; base < total4; base += stride) {
        int m[8];
#pragma unroll
        for (int k = 0; k < 8; ++k)
            m[k] = map[(base + (long long)(k << 8)) >> lg];   // batched loads
#pragma unroll
        for (int k = 0; k < 8; ++k) {
            long long u = base + (long long)(k << 8);
            f4 v;
            if (m[k] >= 0) {
                v = attr[((size_t)m[k] << lg) + d4];
            } else {
                long long c = u >> lg;
                int j = (int)c & Nm1;
                int i = (int)(c >> lgN) & Nm1;
                v = (j == i) ? v1 : v2;
            }
            out[u] = v;            // every lane stores: dense granules
        }
    }
}

// ---------------- uniform 2-pass (R10) ----------------

__global__ __launch_bounds__(256) void fill_u_kernel(
        f4* __restrict__ out, const f4* __restrict__ emb,
        long long total4, int D4, int lg, int lgN) {
    long long base0 = ((long long)blockIdx.x << 11) + threadIdx.x;
    long long stride = (long long)gridDim.x << 11;
    int d4 = (int)base0 & (D4 - 1);
    f4 v1 = emb[D4 + d4];
    f4 v2 = emb[2 * D4 + d4];
    int Nm1 = (1 << lgN) - 1;
    for (long long base = base0; base < total4; base += stride) {
#pragma unroll
        for (int k = 0; k < 8; ++k) {
            long long u = base + (long long)(k << 8);
            long long c = u >> lg;
            int j = (int)c & Nm1;
            int i = (int)(c >> lgN) & Nm1;
            out[u] = (j == i) ? v1 : v2;
        }
    }
}

__global__ __launch_bounds__(256) void edge_u_kernel(
        const f4* __restrict__ attr, const int* __restrict__ eidx,
        f4* __restrict__ out, int E, int N, int D4, int lg) {
    long long idx = (long long)blockIdx.x * 256 + threadIdx.x;
    if (idx < ((long long)E << lg)) {
        int e  = (int)(idx >> lg);
        int d4 = (int)idx & (D4 - 1);
        int s = eidx[e];
        int d = eidx[E + e];
        int dj = d & (N - 1);
        out[(((size_t)s * N + dj) << lg) + d4] = attr[((size_t)e << lg) + d4];
    }
}

// ---------------- generic fast path (R8) ----------------

__global__ __launch_bounds__(256) void fillprep_kernel(
        f4* __restrict__ out, const f4* __restrict__ emb,
        const int* __restrict__ batch, int* __restrict__ offs,
        int TN, int B, int D4, int fillBlocks) {
    if ((int)blockIdx.x == fillBlocks) {
        __shared__ int cnt[1024];
        for (int i = threadIdx.x; i < B; i += 256) cnt[i] = 0;
        __syncthreads();
        for (int v = threadIdx.x; v < TN; v += 256)
            atomicAdd(&cnt[batch[v]], 1);
        __syncthreads();
        if (threadIdx.x == 0) {
            int acc = 0;
            for (int g = 0; g < B; ++g) { offs[g] = acc; acc += cnt[g]; }
            offs[B] = acc;
        }
        return;
    }
    size_t base = ((size_t)blockIdx.x << 10) + threadIdx.x;
    f4 v2 = emb[2 * D4 + (int)(base & (D4 - 1))];
#pragma unroll
    for (int k = 0; k < 4; ++k)
        out[base + (size_t)k * 256] = v2;
}

__global__ __launch_bounds__(256) void diagedge_kernel(
        const f4* __restrict__ attr, const f4* __restrict__ emb,
        const int* __restrict__ eidx, const int* __restrict__ batch,
        const int* __restrict__ offs, f4* __restrict__ out,
        int E, int N, int TN, int D4, int lg) {
    long long idx = (long long)blockIdx.x * 256 + threadIdx.x;
    long long dUnits = (long long)TN << lg;
    if (idx < dUnits) {
        int n  = (int)(idx >> lg);
        int d4 = (int)idx & (D4 - 1);
        int g = batch[n];
        int i = n - offs[g];
        size_t row = (size_t)(g * N + i);
        out[(row * N + i) * D4 + d4] = emb[D4 + d4];
        return;
    }
    idx -= dUnits;
    if (idx < ((long long)E << lg)) {
        int e  = (int)(idx >> lg);
        int d4 = (int)idx & (D4 - 1);
        int s = eidx[e], d = eidx[E + e];
        int g = batch[s];
        int off = offs[g];
        size_t row = (size_t)(g * N + (s - off));
        out[(row * N + (d - off)) * D4 + d4] = attr[((size_t)e << lg) + d4];
    }
}

// ---------------- fallback (R1 structure) ----------------

__global__ void prep_kernel(const int* __restrict__ batch, int* __restrict__ ws,
                            int TN, int B) {
    extern __shared__ int cnt[];
    for (int i = threadIdx.x; i < B; i += blockDim.x) cnt[i] = 0;
    __syncthreads();
    for (int v = threadIdx.x; v < TN; v += blockDim.x)
        atomicAdd(&cnt[batch[v]], 1);
    __syncthreads();
    if (threadIdx.x == 0) {
        int acc = 0;
        for (int g = 0; g < B; ++g) {
            int c = cnt[g];
            ws[g] = acc; ws[B + g] = c; acc += c;
        }
    }
}

__global__ void fill_kernel(f4* __restrict__ out, const f4* __restrict__ emb,
                            const int* __restrict__ counts, int N, int D4, int jPer) {
    int g  = blockIdx.z;
    int i  = blockIdx.y;
    int d4 = threadIdx.x % D4;
    int jj = threadIdx.x / D4;
    int j  = blockIdx.x * jPer + jj;
    if (j >= N) return;
    f4 v1 = emb[D4 + d4];
    f4 v2 = emb[2 * D4 + d4];
    bool diag = (j == i) && (i < counts[g]);
    f4 v = diag ? v1 : v2;
    size_t row = (size_t)(g * N + i);
    out[(row * N + j) * D4 + d4] = v;
}

__global__ void edge_kernel(const f4* __restrict__ attr, const int* __restrict__ eidx,
                            const int* __restrict__ batch, const int* __restrict__ offs,
                            f4* __restrict__ out, int E, int N, int D4) {
    int idx = blockIdx.x * blockDim.x + threadIdx.x;
    if (idx >= E * D4) return;
    int e  = idx / D4;
    int d4 = idx - e * D4;
    int s  = eidx[e];
    int d  = eidx[E + e];
    int g  = batch[s];
    int off = offs[g];
    out[(((size_t)g * N + (s - off)) * N + (d - off)) * D4 + d4] =
        attr[(size_t)e * D4 + d4];
}

extern "C" void kernel_launch(void* const* d_in, const int* in_sizes, int n_in,
                              void* d_out, int out_size, void* d_ws, size_t ws_size,
                              hipStream_t stream) {
    const float* edge_attr  = (const float*)d_in[0];
    const float* emb_table  = (const float*)d_in[1];
    const int*   edge_index = (const int*)d_in[2];
    const int*   batch_vec  = (const int*)d_in[3];

    int D  = in_sizes[1] / 3;                 // emb_table [3, D]
    int E  = in_sizes[2] / 2;                 // edge_index [2, E]
    int TN = in_sizes[3];                     // total nodes
    int D4 = D / 4;
    int N  = (int)((long long)out_size / ((long long)TN * (long long)D));
    int B  = TN / N;

    f4*  out = (f4*)d_out;
    int* ws  = (int*)d_ws;

    auto ispow2 = [](int x) { return x > 0 && (x & (x - 1)) == 0; };
    long long total4 = (long long)out_size / 4;
    bool pow2D4 = ispow2(D4) && D4 <= 256 && (D % 4 == 0);
    int lg = 0; while ((1 << lg) < D4) ++lg;
    int lgN = 0; while ((1 << lgN) < N) ++lgN;

    bool uniform = pow2D4 && ispow2(N) && ((long long)B * N == TN) &&
                   (total4 % 2048 == 0);
    long long cells = (long long)TN * N;
    bool haveMapWs = (long long)ws_size >= cells * 4 && (cells % 4 == 0);

    if (uniform && haveMapWs) {
        int* map = ws;
        long long n4 = cells / 4;
        int iBlocks = (int)((n4 + 255) / 256); if (iBlocks > 2048) iBlocks = 2048;
        mapinit_kernel<<<iBlocks, 256, 0, stream>>>((int4*)map, n4);
        mapscat_kernel<<<(E + 255) / 256, 256, 0, stream>>>(edge_index, map, E, N);

        long long chunks = total4 >> 11;
        int fgrid = (int)(chunks < 2048 ? chunks : 2048);
        fused_u_kernel<<<fgrid, 256, 0, stream>>>(
            (const f4*)edge_attr, (const f4*)emb_table, map, out,
            total4, D4, lg, lgN);
        return;
    }

    if (uniform) {
        long long chunks = total4 >> 11;
        int fgrid = (int)(chunks < 2048 ? chunks : 2048);
        fill_u_kernel<<<fgrid, 256, 0, stream>>>(out, (const f4*)emb_table,
                                                 total4, D4, lg, lgN);
        long long eUnits = (long long)E << lg;
        int bBlocks = (int)((eUnits + 255) / 256);
        edge_u_kernel<<<bBlocks, 256, 0, stream>>>(
            (const f4*)edge_attr, edge_index, out, E, N, D4, lg);
        return;
    }

    bool fast = pow2D4 && (total4 % 1024 == 0) && B <= 1024 &&
                (long long)ws_size >= (long long)(B + 1) * 4;

    if (fast) {
        int fillBlocks = (int)(total4 >> 10);
        fillprep_kernel<<<fillBlocks + 1, 256, 0, stream>>>(
            out, (const f4*)emb_table, batch_vec, ws, TN, B, D4, fillBlocks);

        long long tUnits = ((long long)TN << lg) + ((long long)E << lg);
        int bBlocks = (int)((tUnits + 255) / 256);
        diagedge_kernel<<<bBlocks, 256, 0, stream>>>(
            (const f4*)edge_attr, (const f4*)emb_table, edge_index, batch_vec,
            ws, out, E, N, TN, D4, lg);
    } else {
        prep_kernel<<<1, 1024, (size_t)B * sizeof(int), stream>>>(batch_vec, ws, TN, B);
        int jPer = 256 / D4; if (jPer < 1) jPer = 1;
        dim3 fgrid((N + jPer - 1) / jPer, N, B);
        fill_kernel<<<fgrid, 256, 0, stream>>>(out, (const f4*)emb_table,
                                               ws + B, N, D4, jPer);
        long long eunits = (long long)E * D4;
        int eblocks = (int)((eunits + 255) / 256);
        edge_kernel<<<eblocks, 256, 0, stream>>>((const f4*)edge_attr, edge_index,
                                                 batch_vec, ws, out, E, N, D4);
    }
}

// Round 12
// 60.958 us; speedup vs baseline: 1.3358x; 1.3358x over previous
//
#include <hip/hip_runtime.h>

// out[g,i,j,:] = edge_attr[e] at edge cells (unique, off-diag -> overwrite)
//             + emb_table[1] on in-graph diagonal, emb_table[2] elsewhere.
// Uniform path (TN == B*N, pow2 N/D): persistent grid-stride fill with
// dwordx2 stores (width experiment vs R10's dwordx4), diag inline; then
// edge overwrite (f4). Generic/fallback paths preserved.

typedef float f4 __attribute__((ext_vector_type(4)));
typedef float f2 __attribute__((ext_vector_type(2)));

// ---------------- uniform path ----------------

// b64-store fill: per iter each block covers 4096 f2 units (32KB), 16/thread.
__global__ __launch_bounds__(256) void fill_u2_kernel(
        f2* __restrict__ out, const f2* __restrict__ emb,
        long long total2, int D2, int lgD2, int lgN) {
    long long base0 = ((long long)blockIdx.x << 12) + threadIdx.x;
    long long stride = (long long)gridDim.x << 12;
    int d2 = (int)base0 & (D2 - 1);
    f2 v1 = emb[D2 + d2];          // diag value
    f2 v2 = emb[2 * D2 + d2];      // background value
    int Nm1 = (1 << lgN) - 1;
    for (long long base = base0; base < total2; base += stride) {
#pragma unroll
        for (int k = 0; k < 16; ++k) {
            long long u = base + (long long)(k << 8);
            long long c = u >> lgD2;               // cell = rowg*N + j
            int j = (int)c & Nm1;
            int i = (int)(c >> lgN) & Nm1;
            out[u] = (j == i) ? v1 : v2;
        }
    }
}

// R10 b128 fill kept for non-matching shapes
__global__ __launch_bounds__(256) void fill_u_kernel(
        f4* __restrict__ out, const f4* __restrict__ emb,
        long long total4, int D4, int lg, int lgN) {
    long long base0 = ((long long)blockIdx.x << 11) + threadIdx.x;
    long long stride = (long long)gridDim.x << 11;
    int d4 = (int)base0 & (D4 - 1);
    f4 v1 = emb[D4 + d4];
    f4 v2 = emb[2 * D4 + d4];
    int Nm1 = (1 << lgN) - 1;
    for (long long base = base0; base < total4; base += stride) {
#pragma unroll
        for (int k = 0; k < 8; ++k) {
            long long u = base + (long long)(k << 8);
            long long c = u >> lg;
            int j = (int)c & Nm1;
            int i = (int)(c >> lgN) & Nm1;
            out[u] = (j == i) ? v1 : v2;
        }
    }
}

__global__ __launch_bounds__(256) void edge_u_kernel(
        const f4* __restrict__ attr, const int* __restrict__ eidx,
        f4* __restrict__ out, int E, int N, int D4, int lg) {
    long long idx = (long long)blockIdx.x * 256 + threadIdx.x;
    if (idx < ((long long)E << lg)) {
        int e  = (int)(idx >> lg);
        int d4 = (int)idx & (D4 - 1);
        int s = eidx[e];                    // global src == global row id
        int d = eidx[E + e];
        int dj = d & (N - 1);               // local dst
        out[(((size_t)s * N + dj) << lg) + d4] = attr[((size_t)e << lg) + d4];
    }
}

// ---------------- generic fast path (R8) ----------------

__global__ __launch_bounds__(256) void fillprep_kernel(
        f4* __restrict__ out, const f4* __restrict__ emb,
        const int* __restrict__ batch, int* __restrict__ offs,
        int TN, int B, int D4, int fillBlocks) {
    if ((int)blockIdx.x == fillBlocks) {
        __shared__ int cnt[1024];
        for (int i = threadIdx.x; i < B; i += 256) cnt[i] = 0;
        __syncthreads();
        for (int v = threadIdx.x; v < TN; v += 256)
            atomicAdd(&cnt[batch[v]], 1);
        __syncthreads();
        if (threadIdx.x == 0) {
            int acc = 0;
            for (int g = 0; g < B; ++g) { offs[g] = acc; acc += cnt[g]; }
            offs[B] = acc;
        }
        return;
    }
    size_t base = ((size_t)blockIdx.x << 10) + threadIdx.x;
    f4 v2 = emb[2 * D4 + (int)(base & (D4 - 1))];
#pragma unroll
    for (int k = 0; k < 4; ++k)
        out[base + (size_t)k * 256] = v2;
}

__global__ __launch_bounds__(256) void diagedge_kernel(
        const f4* __restrict__ attr, const f4* __restrict__ emb,
        const int* __restrict__ eidx, const int* __restrict__ batch,
        const int* __restrict__ offs, f4* __restrict__ out,
        int E, int N, int TN, int D4, int lg) {
    long long idx = (long long)blockIdx.x * 256 + threadIdx.x;
    long long dUnits = (long long)TN << lg;
    if (idx < dUnits) {
        int n  = (int)(idx >> lg);
        int d4 = (int)idx & (D4 - 1);
        int g = batch[n];
        int i = n - offs[g];
        size_t row = (size_t)(g * N + i);
        out[(row * N + i) * D4 + d4] = emb[D4 + d4];
        return;
    }
    idx -= dUnits;
    if (idx < ((long long)E << lg)) {
        int e  = (int)(idx >> lg);
        int d4 = (int)idx & (D4 - 1);
        int s = eidx[e], d = eidx[E + e];
        int g = batch[s];
        int off = offs[g];
        size_t row = (size_t)(g * N + (s - off));
        out[(row * N + (d - off)) * D4 + d4] = attr[((size_t)e << lg) + d4];
    }
}

// ---------------- fallback (R1 structure) ----------------

__global__ void prep_kernel(const int* __restrict__ batch, int* __restrict__ ws,
                            int TN, int B) {
    extern __shared__ int cnt[];
    for (int i = threadIdx.x; i < B; i += blockDim.x) cnt[i] = 0;
    __syncthreads();
    for (int v = threadIdx.x; v < TN; v += blockDim.x)
        atomicAdd(&cnt[batch[v]], 1);
    __syncthreads();
    if (threadIdx.x == 0) {
        int acc = 0;
        for (int g = 0; g < B; ++g) {
            int c = cnt[g];
            ws[g] = acc; ws[B + g] = c; acc += c;
        }
    }
}

__global__ void fill_kernel(f4* __restrict__ out, const f4* __restrict__ emb,
                            const int* __restrict__ counts, int N, int D4, int jPer) {
    int g  = blockIdx.z;
    int i  = blockIdx.y;
    int d4 = threadIdx.x % D4;
    int jj = threadIdx.x / D4;
    int j  = blockIdx.x * jPer + jj;
    if (j >= N) return;
    f4 v1 = emb[D4 + d4];
    f4 v2 = emb[2 * D4 + d4];
    bool diag = (j == i) && (i < counts[g]);
    f4 v = diag ? v1 : v2;
    size_t row = (size_t)(g * N + i);
    out[(row * N + j) * D4 + d4] = v;
}

__global__ void edge_kernel(const f4* __restrict__ attr, const int* __restrict__ eidx,
                            const int* __restrict__ batch, const int* __restrict__ offs,
                            f4* __restrict__ out, int E, int N, int D4) {
    int idx = blockIdx.x * blockDim.x + threadIdx.x;
    if (idx >= E * D4) return;
    int e  = idx / D4;
    int d4 = idx - e * D4;
    int s  = eidx[e];
    int d  = eidx[E + e];
    int g  = batch[s];
    int off = offs[g];
    out[(((size_t)g * N + (s - off)) * N + (d - off)) * D4 + d4] =
        attr[(size_t)e * D4 + d4];
}

extern "C" void kernel_launch(void* const* d_in, const int* in_sizes, int n_in,
                              void* d_out, int out_size, void* d_ws, size_t ws_size,
                              hipStream_t stream) {
    const float* edge_attr  = (const float*)d_in[0];
    const float* emb_table  = (const float*)d_in[1];
    const int*   edge_index = (const int*)d_in[2];
    const int*   batch_vec  = (const int*)d_in[3];

    int D  = in_sizes[1] / 3;                 // emb_table [3, D]
    int E  = in_sizes[2] / 2;                 // edge_index [2, E]
    int TN = in_sizes[3];                     // total nodes
    int D4 = D / 4;
    int N  = (int)((long long)out_size / ((long long)TN * (long long)D));
    int B  = TN / N;

    f4*  out = (f4*)d_out;
    int* ws  = (int*)d_ws;

    auto ispow2 = [](int x) { return x > 0 && (x & (x - 1)) == 0; };
    long long total4 = (long long)out_size / 4;
    bool pow2D4 = ispow2(D4) && D4 <= 256 && (D % 4 == 0);
    int lg = 0; while ((1 << lg) < D4) ++lg;
    int lgN = 0; while ((1 << lgN) < N) ++lgN;

    bool uniform = pow2D4 && ispow2(N) && ((long long)B * N == TN) &&
                   (total4 % 2048 == 0);

    if (uniform) {
        int D2 = D / 2;
        long long total2 = (long long)out_size / 2;
        bool w2ok = ispow2(D2) && D2 <= 256 && (D % 2 == 0) &&
                    (total2 % 4096 == 0);
        if (w2ok) {
            int lgD2 = 0; while ((1 << lgD2) < D2) ++lgD2;
            long long chunks = total2 >> 12;
            int fgrid = (int)(chunks < 2048 ? chunks : 2048);
            fill_u2_kernel<<<fgrid, 256, 0, stream>>>(
                (f2*)out, (const f2*)emb_table, total2, D2, lgD2, lgN);
        } else {
            long long chunks = total4 >> 11;
            int fgrid = (int)(chunks < 2048 ? chunks : 2048);
            fill_u_kernel<<<fgrid, 256, 0, stream>>>(out, (const f4*)emb_table,
                                                     total4, D4, lg, lgN);
        }

        long long eUnits = (long long)E << lg;
        int bBlocks = (int)((eUnits + 255) / 256);
        edge_u_kernel<<<bBlocks, 256, 0, stream>>>(
            (const f4*)edge_attr, edge_index, out, E, N, D4, lg);
        return;
    }

    bool fast = pow2D4 && (total4 % 1024 == 0) && B <= 1024 &&
                (long long)ws_size >= (long long)(B + 1) * 4;

    if (fast) {
        int fillBlocks = (int)(total4 >> 10);
        fillprep_kernel<<<fillBlocks + 1, 256, 0, stream>>>(
            out, (const f4*)emb_table, batch_vec, ws, TN, B, D4, fillBlocks);

        long long tUnits = ((long long)TN << lg) + ((long long)E << lg);
        int bBlocks = (int)((tUnits + 255) / 256);
        diagedge_kernel<<<bBlocks, 256, 0, stream>>>(
            (const f4*)edge_attr, (const f4*)emb_table, edge_index, batch_vec,
            ws, out, E, N, TN, D4, lg);
    } else {
        prep_kernel<<<1, 1024, (size_t)B * sizeof(int), stream>>>(batch_vec, ws, TN, B);
        int jPer = 256 / D4; if (jPer < 1) jPer = 1;
        dim3 fgrid((N + jPer - 1) / jPer, N, B);
        fill_kernel<<<fgrid, 256, 0, stream>>>(out, (const f4*)emb_table,
                                               ws + B, N, D4, jPer);
        long long eunits = (long long)E * D4;
        int eblocks = (int)((eunits + 255) / 256);
        edge_kernel<<<eblocks, 256, 0, stream>>>((const f4*)edge_attr, edge_index,
                                                 batch_vec, ws, out, E, N, D4);
    }
}